// Round 6
// baseline (582.225 us; speedup 1.0000x reference)
//
#include <hip/hip_runtime.h>

#define BB 64
#define TT 1024
#define CC 2
#define NN 128

#define REP16(M) M(0)M(1)M(2)M(3)M(4)M(5)M(6)M(7)M(8)M(9)M(10)M(11)M(12)M(13)M(14)M(15)

// fp32 -> bf16 bits, round-to-nearest-even (inputs are never NaN here)
static __device__ __forceinline__ unsigned f2bf(float x) {
    const unsigned u = __float_as_uint(x);
    return (u + 0x7FFFu + ((u >> 16) & 1u)) >> 16;
}
static __device__ __forceinline__ unsigned pk2(float lo, float hi) {
    return f2bf(lo) | (f2bf(hi) << 16);
}

// D.f32 += S0.bf16[0]*S1.bf16[0] + S0.bf16[1]*S1.bf16[1]  (VOP3P, full rate)
#define DOT(acc, pp, ee) \
    asm("v_dot2_f32_bf16 %0, %1, %2, %0" : "+v"(acc) : "v"(pp), "v"(ee));

// Chunk k covers i = 8k..8k+7, packed as bf16 (i,i+1) pairs, for this lane's
// two tags j0=2L (ea) and j1=2L+1 (eb): 16 chunks x 2 tags x uint4 = 128 VGPRs.
#define E_INIT(k) \
    uint4 ea##k, eb##k; \
    ea##k.x = pk2(__expf(tr[(8*(k)+0)*NN + j0]), __expf(tr[(8*(k)+1)*NN + j0])); \
    ea##k.y = pk2(__expf(tr[(8*(k)+2)*NN + j0]), __expf(tr[(8*(k)+3)*NN + j0])); \
    ea##k.z = pk2(__expf(tr[(8*(k)+4)*NN + j0]), __expf(tr[(8*(k)+5)*NN + j0])); \
    ea##k.w = pk2(__expf(tr[(8*(k)+6)*NN + j0]), __expf(tr[(8*(k)+7)*NN + j0])); \
    eb##k.x = pk2(__expf(tr[(8*(k)+0)*NN + j1]), __expf(tr[(8*(k)+1)*NN + j1])); \
    eb##k.y = pk2(__expf(tr[(8*(k)+2)*NN + j1]), __expf(tr[(8*(k)+3)*NN + j1])); \
    eb##k.z = pk2(__expf(tr[(8*(k)+4)*NN + j1]), __expf(tr[(8*(k)+5)*NN + j1])); \
    eb##k.w = pk2(__expf(tr[(8*(k)+6)*NN + j1]), __expf(tr[(8*(k)+7)*NN + j1]));

#define E_PIN(k) \
    asm volatile("" : "+v"(ea##k.x), "+v"(ea##k.y), "+v"(ea##k.z), "+v"(ea##k.w)); \
    asm volatile("" : "+v"(eb##k.x), "+v"(eb##k.y), "+v"(eb##k.z), "+v"(eb##k.w));

// One broadcast b128 (4 packed p-pairs = i 8k..8k+7) + 8 dot2 (4 per tag).
#define MV(k) { const uint4 q = pb[(k)]; \
    DOT(a0, q.x, ea##k.x) DOT(a1, q.y, ea##k.y) \
    DOT(a2, q.z, ea##k.z) DOT(a3, q.w, ea##k.w) \
    DOT(b0, q.x, eb##k.x) DOT(b1, q.y, eb##k.y) \
    DOT(b2, q.z, eb##k.z) DOT(b3, q.w, eb##k.w) }

// ONE WAVE (64 lanes) per (b,c) chain; lane L owns adjacent tags 2L, 2L+1.
// Zero barriers: wave lockstep + in-order DS pipe + compiler lgkmcnt ordering.
// shift = readfirstlane(alpha[tag 0]) — fresh, no LDS hop, exact rescaling.
// NO __launch_bounds__: its waves-per-eu MIN conflicts with (and silently
// drops) amdgpu_waves_per_eu, leaving the RA at its ~8-wave occupancy target
// (budget ~48 VGPR) — the root cause of E spilling in rounds 2-5
// (VGPR_Count 96/56/172/44, all << E footprint). waves_per_eu(1,1) alone
// gives the allocator the full 512-reg budget.
__global__ void
__attribute__((amdgpu_flat_work_group_size(64, 64), amdgpu_waves_per_eu(1, 1)))
crf_logz_kernel(const float* __restrict__ emissions,
                const int* __restrict__ lengths,
                const float* __restrict__ transitions,
                const float* __restrict__ start_trans,
                const float* __restrict__ end_trans,
                float* __restrict__ out)
{
    const int bc = blockIdx.x;
    const int b  = bc >> 1;
    const int c  = bc & 1;
    const int L  = threadIdx.x;        // 0..63
    const int j0 = 2 * L;
    const int j1 = 2 * L + 1;

    __shared__ __align__(16) unsigned pbuf[2][64];  // packed bf16 p-pairs, dbuf

    const float* tr = transitions + c * NN * NN;
    REP16(E_INIT)                      // 128 packed VGPRs of exp(trans)
    REP16(E_PIN)

    const int len  = lengths[b];       // in [T/2, T]
    const int tmax = len - 1;

    // emissions[b][t][c][*]; t-stride = CC*NN floats; float2 per lane, coalesced
    const float* emisb = emissions + ((size_t)b * TT * CC + c) * NN;

    float alpha0 = start_trans[c * NN + j0] + emisb[j0];
    float alpha1 = start_trans[c * NN + j1] + emisb[j1];

    // 2-deep register emission pipeline
    const int t1 = (1 < tmax) ? 1 : tmax, t2 = (2 < tmax) ? 2 : tmax;
    float2 ecur = *(const float2*)&emisb[(size_t)t1 * (CC * NN) + j0];
    float2 enx  = *(const float2*)&emisb[(size_t)t2 * (CC * NN) + j0];

    for (int t = 1; t < len; ++t) {
        // prefetch emissions for t+2 (clamped; ~2 steps of latency cover)
        const int tp = (t + 2 <= tmax) ? (t + 2) : tmax;
        const float2 el = *(const float2*)&emisb[(size_t)tp * (CC * NN) + j0];

        // fresh shift: SGPR broadcast of lane0's alpha0 (= alpha of tag 0)
        const float shift =
            __int_as_float(__builtin_amdgcn_readfirstlane(__float_as_int(alpha0)));
        pbuf[t & 1][L] = pk2(__expf(alpha0 - shift), __expf(alpha1 - shift));
        __builtin_amdgcn_wave_barrier();   // keep reads scheduled below the write

        const uint4* __restrict__ pb = (const uint4*)pbuf[t & 1];
        float a0 = 0.f, a1 = 0.f, a2 = 0.f, a3 = 0.f;
        float b0 = 0.f, b1 = 0.f, b2 = 0.f, b3 = 0.f;
        REP16(MV)                          // 16 broadcast b128 + 128 dot2

        alpha0 = shift + __logf((a0 + a1) + (a2 + a3)) + ecur.x;
        alpha1 = shift + __logf((b0 + b1) + (b2 + b3)) + ecur.y;
        ecur = enx; enx = el;
    }

    // final logsumexp over all 128 tags (2 per lane), pure shuffles
    const float x0 = alpha0 + end_trans[c * NN + j0];
    const float x1 = alpha1 + end_trans[c * NN + j1];
    float m = fmaxf(x0, x1);
    #pragma unroll
    for (int off = 32; off > 0; off >>= 1)
        m = fmaxf(m, __shfl_xor(m, off));
    float s = __expf(x0 - m) + __expf(x1 - m);
    #pragma unroll
    for (int off = 32; off > 0; off >>= 1)
        s += __shfl_xor(s, off);
    if (L == 0) out[b * CC + c] = m + __logf(s);
}

extern "C" void kernel_launch(void* const* d_in, const int* in_sizes, int n_in,
                              void* d_out, int out_size, void* d_ws, size_t ws_size,
                              hipStream_t stream) {
    const float* emissions   = (const float*)d_in[0];
    const int*   lengths     = (const int*)d_in[1];
    const float* transitions = (const float*)d_in[2];
    const float* start_t     = (const float*)d_in[3];
    const float* end_t       = (const float*)d_in[4];
    float* out = (float*)d_out;

    crf_logz_kernel<<<BB * CC, 64, 0, stream>>>(
        emissions, lengths, transitions, start_t, end_t, out);
}